// Round 6
// baseline (273.370 us; speedup 1.0000x reference)
//
#include <hip/hip_runtime.h>
#include <stdint.h>

typedef unsigned long long u64;
typedef unsigned int u32;
typedef float f32x2 __attribute__((ext_vector_type(2)));
typedef float f32x4 __attribute__((ext_vector_type(4)));

constexpr int kC  = 256;
constexpr int kHW = 3136;             // 56*56
constexpr int kN  = 32;
constexpr int kP  = kN * kHW;         // 100352 spatial positions
constexpr int kPos = 128;             // positions per block (2/lane, f32x2 never straddles n)
constexpr int kBlk = kP / kPos;       // 784 blocks -> 12.25 waves/CU
constexpr int kRedBlk  = 16;          // reduce blocks
constexpr int kRedRows = kBlk / kRedBlk;  // 49

// d_ws layout (bytes):
constexpr size_t OFF_T     = 0;        // u64 [256][4]  w-sign planes, O-MAJOR (s_load_dwordx8-able)
constexpr size_t OFF_SCALE = 8192;     // f32 [256]
constexpr size_t OFF_SUMD  = 9216;     // i64 [256]  sum of dot
constexpr size_t OFF_SUMD2 = 11264;    // i64 [256]  sum of dot^2
constexpr size_t OFF_CC    = 13312;    // f32x4 [256] {2cA, cB, alpha, bias2}
constexpr size_t OFF_PS    = 17408;    // i32 [784][256] per-block sum(128-q) partials
constexpr size_t OFF_PQ    = 820224;   // i32 [784][256] per-block sum(128-q)^2 partials
constexpr size_t OFF_D     = 1623040;  // u32 [256][kP/2] packed {q0,q1} mismatch counts

struct alignas(16) U64x2 { u64 x, y; };

// ---------------------------------------------------------------------------
// Kernel A: w-prep. 16 blocks x 256. Builds T4 (o-major w-sign planes) +
// scale; block 0 zeros the stat accumulators. ~2 us.
// ---------------------------------------------------------------------------
__global__ __launch_bounds__(256) void prep_kernel(
    const float* __restrict__ w, char* __restrict__ ws) {
  int t = threadIdx.x;
  int b = blockIdx.x;
  u64*   T4    = (u64*)(ws + OFF_T);
  float* scale = (float*)(ws + OFF_SCALE);
  int kk = t >> 6, ln = t & 63;
  if (b == 0) {
    ((u64*)(ws + OFF_SUMD))[t]  = 0ull;
    ((u64*)(ws + OFF_SUMD2))[t] = 0ull;
  }
  __shared__ float part[4][16];
#pragma unroll
  for (int i = 0; i < 16; ++i) {
    int o = b * 16 + i;
    float v = w[o * kC + kk * 64 + ln];   // coalesced 256B/wave
    u64 m = __ballot(v >= 0.0f);
    float a = fabsf(v);
#pragma unroll
    for (int s = 32; s > 0; s >>= 1) a += __shfl_xor(a, s, 64);
    if (ln == 0) { T4[o * 4 + kk] = m; part[kk][i] = a; }
  }
  __syncthreads();
  if (t < 16) {
    int o = b * 16 + t;
    scale[o] = (part[0][t] + part[1][t] + part[2][t] + part[3][t]) * (1.0f / 256.0f);
  }
}

// ---------------------------------------------------------------------------
// Kernel B: pack + dot-counts + stats partials, all in one x-pass.
// Phase 1: wave k packs plane k (64 channels) for the block's 128 positions
//   (2/lane, f32x2 loads) -> 4 KB LDS mask tile.
// Phase 2: lane pulls its 2 positions' 4-plane masks into regs (4 ds_read),
//   then loops its wave's 64 output channels: T4[o] via wave-uniform s_load,
//   8 xor+popc -> q0,q1; D store is 256 B/wave contiguous; per-o stats are
//   butterfly-reduced in-register (NO stats pass, NO extra S traffic).
// All popc VALU hides under this kernel's own HBM time.
// ---------------------------------------------------------------------------
__global__ __launch_bounds__(256) void pack_d_kernel(
    const float* __restrict__ x, const float* __restrict__ bias0,
    char* __restrict__ ws) {
  __shared__ U64x2 tile[4][64];        // [plane][lane] masks, 4 KB
  int t = threadIdx.x;
  int k    = __builtin_amdgcn_readfirstlane(t >> 6);  // wave-uniform plane
  int lane = t & 63;
  u32 pb = (u32)blockIdx.x * (u32)kPos;
  u32 p0 = pb + 2u * (u32)lane;
  u32 n  = p0 / kHW;                   // per-lane (tile may straddle n)
  u32 hw = p0 - n * kHW;               // even -> 8B aligned, never straddles row
  const float* xp = x + (size_t)(n * kC + k * 64) * kHW + hw;
  const float* bp = bias0 + k * 64;    // uniform -> s_load

  u64 m0 = 0, m1 = 0;
#pragma unroll 8
  for (int i = 0; i < 64; ++i) {
    f32x2 v = *(const f32x2*)(xp + (size_t)i * kHW);  // 512 B/wave contiguous
    float bc = bp[i];
    m0 |= (u64)(v.x + bc >= 0.0f) << i;
    m1 |= (u64)(v.y + bc >= 0.0f) << i;
  }
  U64x2 mm; mm.x = m0; mm.y = m1;
  tile[k][lane] = mm;
  __syncthreads();

  U64x2 sa = tile[0][lane], sb = tile[1][lane],
        sc = tile[2][lane], sd = tile[3][lane];

  const u64* T4 = (const u64*)(ws + OFF_T);
  u32* D = (u32*)(ws + OFF_D);
  int myPS = 0, myPQ = 0;
#pragma unroll 4
  for (int i = 0; i < 64; ++i) {
    int o = k * 64 + i;                // wave-uniform -> T4 via s_load
    u64 t0 = T4[4 * o], t1 = T4[4 * o + 1], t2 = T4[4 * o + 2], t3 = T4[4 * o + 3];
    int q0 = __popcll(sa.x ^ t0) + __popcll(sb.x ^ t1) +
             __popcll(sc.x ^ t2) + __popcll(sd.x ^ t3);
    int q1 = __popcll(sa.y ^ t0) + __popcll(sb.y ^ t1) +
             __popcll(sc.y ^ t2) + __popcll(sd.y ^ t3);
    D[(size_t)o * (kP / 2) + (pb >> 1) + lane] = (u32)q0 | ((u32)q1 << 16);
    int a0 = 128 - q0, a1 = 128 - q1;
    int s  = a0 + a1;
    int sq = a0 * a0 + a1 * a1;
#pragma unroll
    for (int msk = 1; msk < 64; msk <<= 1) {
      s  += __shfl_xor(s,  msk, 64);
      sq += __shfl_xor(sq, msk, 64);
    }
    if (lane == i) { myPS = s; myPQ = sq; }   // lane i keeps o = 64k+i (== t)
  }
  ((int*)(ws + OFF_PS))[blockIdx.x * 256 + t] = myPS;   // coalesced 1 KB
  ((int*)(ws + OFF_PQ))[blockIdx.x * 256 + t] = myPQ;   // coalesced 1 KB
}

// ---------------------------------------------------------------------------
// Kernel C: reduce partials. 16 blocks x 256; thread sums 49 rows of its
// channel column (coalesced, L2-resident), then ONE u64 atomic per stat.
// ---------------------------------------------------------------------------
__global__ __launch_bounds__(256) void reduce_kernel(char* __restrict__ ws) {
  int t = threadIdx.x;
  int b = blockIdx.x;
  const int* PS = (const int*)(ws + OFF_PS);
  const int* PQ = (const int*)(ws + OFF_PQ);
  long long s = 0, q = 0;
#pragma unroll 7
  for (int r = 0; r < kRedRows; ++r) {
    int row = b * kRedRows + r;
    s += PS[row * 256 + t];
    q += PQ[row * 256 + t];
  }
  atomicAdd((u64*)(ws + OFF_SUMD) + t,  (u64)(long long)(2 * s));
  atomicAdd((u64*)(ws + OFF_SUMD2) + t, (u64)(long long)(4 * q));
}

// ---------------------------------------------------------------------------
// Kernel D: coefs. 1 block x 256: thread t = channel, writes
// cc = {2cA, cB, alpha, bias2} to ws. ~2 us (mostly launch).
// ---------------------------------------------------------------------------
__global__ __launch_bounds__(256) void coef_kernel(
    const float* __restrict__ gamma, const float* __restrict__ beta,
    const float* __restrict__ bias1, const float* __restrict__ alpha,
    const float* __restrict__ bias2, char* __restrict__ ws) {
  int t = threadIdx.x;
  const float*     scale = (const float*)(ws + OFF_SCALE);
  const long long* sumd  = (const long long*)(ws + OFF_SUMD);
  const long long* sumd2 = (const long long*)(ws + OFF_SUMD2);
  double inv  = 1.0 / (double)kP;
  double md   = (double)sumd[t] * inv;
  double e2   = (double)sumd2[t] * inv;
  double vard = e2 - md * md;
  float sc  = scale[t];
  float mu  = sc * (float)md;
  float var = sc * sc * (float)vard;
  float rs  = rsqrtf(var + 1e-5f);
  float g   = gamma[t];
  float cA  = g * rs * sc;
  float cB  = beta[t] - g * rs * mu + bias1[t];
  f32x4 cc; cc.x = 2.0f * cA; cc.y = cB; cc.z = alpha[t]; cc.w = bias2[t];
  ((f32x4*)(ws + OFF_CC))[t] = cc;
}

// ---------------------------------------------------------------------------
// Kernel E: finalize = PURE STREAM. No LDS, no sync, no popc: per o-iter,
// f32x2 x load + u32 D load (L3-hot) + wave-uniform cc (s_load) + fma +
// NT f32x2 store. u = 2cA*(128-q) + cB + x ; out = PReLU(u) + bias2.
// ---------------------------------------------------------------------------
__global__ __launch_bounds__(256) void finalize_kernel(
    const float* __restrict__ x, const char* __restrict__ ws,
    float* __restrict__ out) {
  int t = threadIdx.x;
  int k    = __builtin_amdgcn_readfirstlane(t >> 6);
  int lane = t & 63;
  u32 pb = (u32)blockIdx.x * (u32)kPos;
  u32 p0 = pb + 2u * (u32)lane;
  u32 n  = p0 / kHW;
  u32 hw = p0 - n * kHW;

  const float* xp = x   + (size_t)(n * kC + k * 64) * kHW + hw;
  float*       op = out + (size_t)(n * kC + k * 64) * kHW + hw;
  const u32*   D  = (const u32*)(ws + OFF_D);
  const f32x4* CC = (const f32x4*)(ws + OFF_CC);
  u32 dbase = (pb >> 1) + (u32)lane;

#pragma unroll 4
  for (int i = 0; i < 64; ++i) {
    int o = k * 64 + i;                 // wave-uniform -> cc via s_load
    f32x4 cc = CC[o];
    u32 d = D[(size_t)o * (kP / 2) + dbase];          // 256 B/wave, L3-hot
    f32x2 xv = *(const f32x2*)(xp + (size_t)i * kHW); // 512 B/wave
    float u0 = fmaf(cc.x, (float)(128 - (int)(d & 0xFFFFu)), cc.y) + xv.x;
    float u1 = fmaf(cc.x, (float)(128 - (int)(d >> 16)),     cc.y) + xv.y;
    f32x2 r;
    r.x = (u0 > 0.0f ? u0 : cc.z * u0) + cc.w;
    r.y = (u1 > 0.0f ? u1 : cc.z * u1) + cc.w;
    __builtin_nontemporal_store(r, (f32x2*)(op + (size_t)i * kHW));
  }
}

extern "C" void kernel_launch(void* const* d_in, const int* in_sizes, int n_in,
                              void* d_out, int out_size, void* d_ws, size_t ws_size,
                              hipStream_t stream) {
  const float* x     = (const float*)d_in[0];
  const float* bias0 = (const float*)d_in[1];
  const float* w     = (const float*)d_in[2];
  const float* gamma = (const float*)d_in[3];
  const float* beta  = (const float*)d_in[4];
  const float* bias1 = (const float*)d_in[5];
  const float* alpha = (const float*)d_in[6];
  const float* bias2 = (const float*)d_in[7];
  float* out = (float*)d_out;
  char*  ws  = (char*)d_ws;

  hipLaunchKernelGGL(prep_kernel, dim3(16), dim3(256), 0, stream, w, ws);
  hipLaunchKernelGGL(pack_d_kernel, dim3(kBlk), dim3(256), 0, stream,
                     x, bias0, ws);
  hipLaunchKernelGGL(reduce_kernel, dim3(kRedBlk), dim3(256), 0, stream, ws);
  hipLaunchKernelGGL(coef_kernel, dim3(1), dim3(256), 0, stream,
                     gamma, beta, bias1, alpha, bias2, ws);
  hipLaunchKernelGGL(finalize_kernel, dim3(kBlk), dim3(256), 0, stream,
                     x, ws, out);
}

// Round 7
// 264.880 us; speedup vs baseline: 1.0321x; 1.0321x over previous
//
#include <hip/hip_runtime.h>
#include <stdint.h>

typedef unsigned long long u64;
typedef unsigned int u32;
typedef float f32x2 __attribute__((ext_vector_type(2)));
typedef float f32x4 __attribute__((ext_vector_type(4)));

constexpr int kC  = 256;
constexpr int kHW = 3136;             // 56*56
constexpr int kN  = 32;
constexpr int kP  = kN * kHW;         // 100352 spatial positions
constexpr int kPos = 128;             // positions per block (2/lane)
constexpr int kBlk = kP / kPos;       // 784 blocks -> 12.25 waves/CU
constexpr int kDW  = kP / 2;          // 50176 u32 D-words per channel (= 196*256)
constexpr int kStIt = kDW / 256;      // 196 iters per stats thread

// d_ws layout (bytes):
constexpr size_t OFF_T     = 0;        // u64 [256][4]  w-sign planes, O-MAJOR
constexpr size_t OFF_SCALE = 8192;     // f32 [256]
constexpr size_t OFF_CC    = 13312;    // f32x4 [256] {2cA, cB, alpha, bias2}
constexpr size_t OFF_D     = 1623040;  // u32 [256][kDW] packed {q0,q1} mismatch counts

struct alignas(16) U64x2 { u64 x, y; };

// ---------------------------------------------------------------------------
// Kernel A: w-prep. 16 blocks x 256. Builds T4 (o-major w-sign planes) +
// scale. ~2 us. (No accumulator zeroing needed anymore: no atomics anywhere.)
// ---------------------------------------------------------------------------
__global__ __launch_bounds__(256) void prep_kernel(
    const float* __restrict__ w, char* __restrict__ ws) {
  int t = threadIdx.x;
  int b = blockIdx.x;
  u64*   T4    = (u64*)(ws + OFF_T);
  float* scale = (float*)(ws + OFF_SCALE);
  int kk = t >> 6, ln = t & 63;
  __shared__ float part[4][16];
#pragma unroll
  for (int i = 0; i < 16; ++i) {
    int o = b * 16 + i;
    float v = w[o * kC + kk * 64 + ln];   // coalesced 256B/wave
    u64 m = __ballot(v >= 0.0f);
    float a = fabsf(v);
#pragma unroll
    for (int s = 32; s > 0; s >>= 1) a += __shfl_xor(a, s, 64);
    if (ln == 0) { T4[o * 4 + kk] = m; part[kk][i] = a; }
  }
  __syncthreads();
  if (t < 16) {
    int o = b * 16 + t;
    scale[o] = (part[0][t] + part[1][t] + part[2][t] + part[3][t]) * (1.0f / 256.0f);
  }
}

// ---------------------------------------------------------------------------
// Kernel B: pack + dot-counts, one x-pass. (R6 structure MINUS the per-iter
// shuffle butterfly -- that was 768 serialized cross-lane ops/thread.)
// Phase 1: wave k packs plane k (64 ch) for 128 positions -> 4 KB LDS tile.
// Phase 2: lane pulls its 2 positions' 4 plane-masks (4 ds_read), loops its
// wave's 64 output channels: T4[o] wave-uniform s_load, 8 xor+popc -> q0,q1,
// D store 256 B/wave contiguous. Pure streaming + local VALU, no cross-lane.
// ---------------------------------------------------------------------------
__global__ __launch_bounds__(256) void pack_d_kernel(
    const float* __restrict__ x, const float* __restrict__ bias0,
    char* __restrict__ ws) {
  __shared__ U64x2 tile[4][64];        // [plane][lane] masks, 4 KB
  int t = threadIdx.x;
  int k    = __builtin_amdgcn_readfirstlane(t >> 6);  // wave-uniform plane
  int lane = t & 63;
  u32 pb = (u32)blockIdx.x * (u32)kPos;
  u32 p0 = pb + 2u * (u32)lane;
  u32 n  = p0 / kHW;                   // per-lane (tile may straddle n)
  u32 hw = p0 - n * kHW;               // even -> 8B aligned, never straddles row
  const float* xp = x + (size_t)(n * kC + k * 64) * kHW + hw;
  const float* bp = bias0 + k * 64;    // uniform -> s_load

  u64 m0 = 0, m1 = 0;
#pragma unroll 8
  for (int i = 0; i < 64; ++i) {
    f32x2 v = *(const f32x2*)(xp + (size_t)i * kHW);  // 512 B/wave contiguous
    float bc = bp[i];
    m0 |= (u64)(v.x + bc >= 0.0f) << i;
    m1 |= (u64)(v.y + bc >= 0.0f) << i;
  }
  U64x2 mm; mm.x = m0; mm.y = m1;
  tile[k][lane] = mm;
  __syncthreads();

  U64x2 sa = tile[0][lane], sb = tile[1][lane],
        sc = tile[2][lane], sd = tile[3][lane];

  const u64* T4 = (const u64*)(ws + OFF_T);
  u32* D = (u32*)(ws + OFF_D);
  u32 dbase = (pb >> 1) + (u32)lane;
#pragma unroll 8
  for (int i = 0; i < 64; ++i) {
    int o = k * 64 + i;                // wave-uniform -> T4 via s_load
    u64 t0 = T4[4 * o], t1 = T4[4 * o + 1], t2 = T4[4 * o + 2], t3 = T4[4 * o + 3];
    int q0 = __popcll(sa.x ^ t0) + __popcll(sb.x ^ t1) +
             __popcll(sc.x ^ t2) + __popcll(sd.x ^ t3);
    int q1 = __popcll(sa.y ^ t0) + __popcll(sb.y ^ t1) +
             __popcll(sc.y ^ t2) + __popcll(sd.y ^ t3);
    D[(size_t)o * kDW + dbase] = (u32)q0 | ((u32)q1 << 16);  // 256 B/wave
  }
}

// ---------------------------------------------------------------------------
// Kernel C: stats + coefs from D. 256 blocks = one per channel o.
// Each thread sums 196 coalesced u32s of D[o] (L3-hot), wave shfl-reduce
// (ONE butterfly per thread, not 64), 4-word LDS tree, thread 0 computes
// the BN coefficients and writes CC[o]. No atomics, no partials.
// ---------------------------------------------------------------------------
__global__ __launch_bounds__(256) void stats_coef_kernel(
    const float* __restrict__ gamma, const float* __restrict__ beta,
    const float* __restrict__ bias1, const float* __restrict__ alpha,
    const float* __restrict__ bias2, char* __restrict__ ws) {
  int t = threadIdx.x;
  int o = blockIdx.x;
  int wid = t >> 6, lane = t & 63;
  const u32* Do = (const u32*)(ws + OFF_D) + (size_t)o * kDW;

  int s = 0, sq = 0;                   // per-thread: <= 50176 / 6.4e6, int-safe
#pragma unroll 14
  for (int j = 0; j < kStIt; ++j) {
    u32 d = Do[j * 256 + t];           // 1 KB/block-iter coalesced, L3-hot
    int a0 = 128 - (int)(d & 0xFFFFu);
    int a1 = 128 - (int)(d >> 16);
    s  += a0 + a1;
    sq += a0 * a0 + a1 * a1;
  }
#pragma unroll
  for (int m = 32; m > 0; m >>= 1) {
    s  += __shfl_down(s,  m, 64);
    sq += __shfl_down(sq, m, 64);
  }
  __shared__ long long wsS[4], wsQ[4];
  if (lane == 0) { wsS[wid] = s; wsQ[wid] = sq; }
  __syncthreads();
  if (t == 0) {
    long long S  = wsS[0] + wsS[1] + wsS[2] + wsS[3];
    long long SQ = wsQ[0] + wsQ[1] + wsQ[2] + wsQ[3];
    // identical math to prior rounds: sumd = 2S, sumd2 = 4SQ
    double inv  = 1.0 / (double)kP;
    double md   = (double)(2ll * S) * inv;
    double e2   = (double)(4ll * SQ) * inv;
    double vard = e2 - md * md;
    float sc  = ((const float*)(ws + OFF_SCALE))[o];
    float mu  = sc * (float)md;
    float var = sc * sc * (float)vard;
    float rs  = rsqrtf(var + 1e-5f);
    float g   = gamma[o];
    float cA  = g * rs * sc;
    float cB  = beta[o] - g * rs * mu + bias1[o];
    f32x4 cc; cc.x = 2.0f * cA; cc.y = cB; cc.z = alpha[o]; cc.w = bias2[o];
    ((f32x4*)(ws + OFF_CC))[o] = cc;
  }
}

// ---------------------------------------------------------------------------
// Kernel D: finalize = PURE STREAM. No LDS, no sync, no popc: per o-iter,
// f32x2 x load + u32 D load (L3-hot) + wave-uniform cc (s_load) + fma +
// NT f32x2 store. u = 2cA*(128-q) + cB + x ; out = PReLU(u) + bias2.
// ---------------------------------------------------------------------------
__global__ __launch_bounds__(256) void finalize_kernel(
    const float* __restrict__ x, const char* __restrict__ ws,
    float* __restrict__ out) {
  int t = threadIdx.x;
  int k    = __builtin_amdgcn_readfirstlane(t >> 6);
  int lane = t & 63;
  u32 pb = (u32)blockIdx.x * (u32)kPos;
  u32 p0 = pb + 2u * (u32)lane;
  u32 n  = p0 / kHW;
  u32 hw = p0 - n * kHW;

  const float* xp = x   + (size_t)(n * kC + k * 64) * kHW + hw;
  float*       op = out + (size_t)(n * kC + k * 64) * kHW + hw;
  const u32*   D  = (const u32*)(ws + OFF_D);
  const f32x4* CC = (const f32x4*)(ws + OFF_CC);
  u32 dbase = (pb >> 1) + (u32)lane;

#pragma unroll 4
  for (int i = 0; i < 64; ++i) {
    int o = k * 64 + i;                 // wave-uniform -> cc via s_load
    f32x4 cc = CC[o];
    u32 d = D[(size_t)o * kDW + dbase];               // 256 B/wave, L3-hot
    f32x2 xv = *(const f32x2*)(xp + (size_t)i * kHW); // 512 B/wave
    float u0 = fmaf(cc.x, (float)(128 - (int)(d & 0xFFFFu)), cc.y) + xv.x;
    float u1 = fmaf(cc.x, (float)(128 - (int)(d >> 16)),     cc.y) + xv.y;
    f32x2 r;
    r.x = (u0 > 0.0f ? u0 : cc.z * u0) + cc.w;
    r.y = (u1 > 0.0f ? u1 : cc.z * u1) + cc.w;
    __builtin_nontemporal_store(r, (f32x2*)(op + (size_t)i * kHW));
  }
}

extern "C" void kernel_launch(void* const* d_in, const int* in_sizes, int n_in,
                              void* d_out, int out_size, void* d_ws, size_t ws_size,
                              hipStream_t stream) {
  const float* x     = (const float*)d_in[0];
  const float* bias0 = (const float*)d_in[1];
  const float* w     = (const float*)d_in[2];
  const float* gamma = (const float*)d_in[3];
  const float* beta  = (const float*)d_in[4];
  const float* bias1 = (const float*)d_in[5];
  const float* alpha = (const float*)d_in[6];
  const float* bias2 = (const float*)d_in[7];
  float* out = (float*)d_out;
  char*  ws  = (char*)d_ws;

  hipLaunchKernelGGL(prep_kernel, dim3(16), dim3(256), 0, stream, w, ws);
  hipLaunchKernelGGL(pack_d_kernel, dim3(kBlk), dim3(256), 0, stream,
                     x, bias0, ws);
  hipLaunchKernelGGL(stats_coef_kernel, dim3(256), dim3(256), 0, stream,
                     gamma, beta, bias1, alpha, bias2, ws);
  hipLaunchKernelGGL(finalize_kernel, dim3(kBlk), dim3(256), 0, stream,
                     x, ws, out);
}

// Round 8
// 244.691 us; speedup vs baseline: 1.1172x; 1.0825x over previous
//
#include <hip/hip_runtime.h>
#include <stdint.h>

typedef unsigned long long u64;
typedef unsigned int u32;
typedef float f32x2 __attribute__((ext_vector_type(2)));

constexpr int kC  = 256;
constexpr int kHW = 3136;             // 56*56
constexpr int kN  = 32;
constexpr int kP  = kN * kHW;         // 100352 spatial positions
constexpr int kPosPk = 128;           // positions per pack block (2/lane, f32x2)
constexpr int kBlkPk = kP / kPosPk;   // 784
constexpr int kPosFn = 64;            // positions per finalize block (1/lane)
constexpr int kBlkFn = kP / kPosFn;   // 1568  (R0's proven finalize geometry)

// d_ws layout (bytes):
constexpr size_t OFF_T     = 0;      // u64 [4][256]  packed w-sign planes (plane-major)
constexpr size_t OFF_SCALE = 8192;   // f32 [256]
constexpr size_t OFF_SUMD  = 9216;   // i64 [256]  sum of dot
constexpr size_t OFF_SUMD2 = 11264;  // i64 [256]  sum of dot^2
constexpr size_t OFF_S     = 13312;  // u64 [4][kP] packed x-sign planes (SoA)

struct alignas(16) U64x2 { u64 x, y; };

// ---------------------------------------------------------------------------
// Kernel A: w-prep. 16 blocks x 256. Builds T (plane-major w-sign planes) +
// scale; block 0 zeros the stat accumulators. ~2 us.
// ---------------------------------------------------------------------------
__global__ __launch_bounds__(256) void prep_kernel(
    const float* __restrict__ w, char* __restrict__ ws) {
  int t = threadIdx.x;
  int b = blockIdx.x;
  u64*   T     = (u64*)(ws + OFF_T);
  float* scale = (float*)(ws + OFF_SCALE);
  int kk = t >> 6, ln = t & 63;
  if (b == 0) {
    ((u64*)(ws + OFF_SUMD))[t]  = 0ull;
    ((u64*)(ws + OFF_SUMD2))[t] = 0ull;
  }
  __shared__ float part[4][16];
#pragma unroll
  for (int i = 0; i < 16; ++i) {
    int o = b * 16 + i;
    float v = w[o * kC + kk * 64 + ln];   // coalesced 256B/wave
    u64 m = __ballot(v >= 0.0f);
    float a = fabsf(v);
#pragma unroll
    for (int s = 32; s > 0; s >>= 1) a += __shfl_xor(a, s, 64);
    if (ln == 0) { T[kk * 256 + o] = m; part[kk][i] = a; }
  }
  __syncthreads();
  if (t < 16) {
    int o = b * 16 + t;
    scale[o] = (part[0][t] + part[1][t] + part[2][t] + part[3][t]) * (1.0f / 256.0f);
  }
}

// ---------------------------------------------------------------------------
// Kernel B: pack + LDS-fed stats, one x-pass.
// Phase 1 (= proven pack_d phase 1): wave k packs plane k for 128 positions
//   (2/lane, f32x2 plain loads -> seed L3 for finalize); masks go to BOTH
//   global S (finalize's input) and a 4 KB LDS tile.
// Phase 2: thread t = channel. T[t] loads are per-thread COALESCED (32 B/
//   lane once); the block's 128 position-masks come from LDS broadcast
//   reads (~6 cyc) instead of R0/R1's ~200-cyc global uniform loads -- the
//   stats dispatch and its S re-read are deleted. 2 atomics/thread (count
//   identical to R0's proven 401K).
// ---------------------------------------------------------------------------
__global__ __launch_bounds__(256) void pack_stats_kernel(
    const float* __restrict__ x, const float* __restrict__ bias0,
    char* __restrict__ ws) {
  __shared__ U64x2 tile[4][64];        // [plane][lane] masks, 4 KB
  int t = threadIdx.x;
  int k    = __builtin_amdgcn_readfirstlane(t >> 6);  // wave-uniform plane
  int lane = t & 63;
  u32 pb = (u32)blockIdx.x * (u32)kPosPk;
  u32 p0 = pb + 2u * (u32)lane;
  u32 n  = p0 / kHW;
  u32 hw = p0 - n * kHW;               // even -> 8B aligned, never straddles row
  const float* xp = x + (size_t)(n * kC + k * 64) * kHW + hw;
  const float* bp = bias0 + k * 64;    // uniform -> s_load

  u64 m0 = 0, m1 = 0;
#pragma unroll 8
  for (int i = 0; i < 64; ++i) {
    f32x2 v = *(const f32x2*)(xp + (size_t)i * kHW);  // 512 B/wave contiguous
    float bc = bp[i];
    m0 |= (u64)(v.x + bc >= 0.0f) << i;
    m1 |= (u64)(v.y + bc >= 0.0f) << i;
  }
  U64x2 mm; mm.x = m0; mm.y = m1;
  tile[k][lane] = mm;
  *(U64x2*)((u64*)(ws + OFF_S) + (size_t)k * kP + p0) = mm;  // 16 B/lane
  __syncthreads();

  const u64* T = (const u64*)(ws + OFF_T);
  u64 t0 = T[t], t1 = T[256 + t], t2 = T[512 + t], t3 = T[768 + t];
  int s = 0, sq = 0;
#pragma unroll 8
  for (int j = 0; j < 64; ++j) {       // LDS broadcast reads, conflict-free
    U64x2 a0 = tile[0][j], a1 = tile[1][j], a2 = tile[2][j], a3 = tile[3][j];
    int ka = __popcll(a0.x ^ t0) + __popcll(a1.x ^ t1) +
             __popcll(a2.x ^ t2) + __popcll(a3.x ^ t3);
    int kb = __popcll(a0.y ^ t0) + __popcll(a1.y ^ t1) +
             __popcll(a2.y ^ t2) + __popcll(a3.y ^ t3);
    int ma = 128 - ka, mb = 128 - kb;
    s  += ma + mb;
    sq += ma * ma + mb * mb;
  }
  atomicAdd((u64*)(ws + OFF_SUMD) + t,  (u64)(long long)(2 * s));
  atomicAdd((u64*)(ws + OFF_SUMD2) + t, (u64)(long long)(4 * sq));
}

// ---------------------------------------------------------------------------
// Kernel C: BN coefs + fused epilogue (R0 proven structure, 1568 blocks).
//   u = 2*cA*m + cB + x ;  out = (u>0 ? u : alpha*u) + bias2
// x loads PLAIN (L3-resident from pack's pass); out stores NT (pure drain).
// ---------------------------------------------------------------------------
__global__ __launch_bounds__(256) void finalize_kernel(
    const float* __restrict__ x, const float* __restrict__ gamma,
    const float* __restrict__ beta, const float* __restrict__ bias1,
    const float* __restrict__ alpha, const float* __restrict__ bias2,
    const char* __restrict__ ws, float* __restrict__ out) {
  __shared__ u64    ldsT[256][4];   // [o][plane]: broadcast ds_read_b128 x2
  __shared__ float4 ldsC[256];      // {2*cA, cB, alpha, bias2}

  int t = threadIdx.x;
  {
    const u64* T = (const u64*)(ws + OFF_T);
#pragma unroll
    for (int q = 0; q < 4; ++q) ldsT[t][q] = T[q * 256 + t];

    const float*     scale = (const float*)(ws + OFF_SCALE);
    const long long* sumd  = (const long long*)(ws + OFF_SUMD);
    const long long* sumd2 = (const long long*)(ws + OFF_SUMD2);
    double inv  = 1.0 / (double)kP;
    double md   = (double)sumd[t] * inv;
    double e2   = (double)sumd2[t] * inv;
    double vard = e2 - md * md;
    float sc  = scale[t];
    float mu  = sc * (float)md;
    float var = sc * sc * (float)vard;
    float rs  = rsqrtf(var + 1e-5f);
    float g   = gamma[t];
    float cA  = g * rs * sc;
    float cB  = beta[t] - g * rs * mu + bias1[t];
    ldsC[t] = make_float4(2.0f * cA, cB, alpha[t], bias2[t]);
  }
  __syncthreads();

  int k    = __builtin_amdgcn_readfirstlane(t >> 6);
  int lane = t & 63;
  u32 p  = blockIdx.x * (u32)kPosFn + (u32)lane;
  u32 n  = p / kHW;
  u32 hw = p - n * kHW;

  const u64* S = (const u64*)(ws + OFF_S);
  u64 s0 = S[p];                       // 8B/lane coalesced, L2/L3-hot
  u64 s1 = S[kP + p];
  u64 s2 = S[2 * kP + p];
  u64 s3 = S[3 * kP + p];

  const float* xp = x   + (size_t)(n * kC + k * 64) * kHW + hw;
  float*       op = out + (size_t)(n * kC + k * 64) * kHW + hw;

#pragma unroll 8
  for (int i = 0; i < 64; ++i) {
    int o = k * 64 + i;                // wave-uniform -> LDS broadcast
    u64 w0 = ldsT[o][0], w1 = ldsT[o][1], w2 = ldsT[o][2], w3 = ldsT[o][3];
    int kx = __popcll(s0 ^ w0) + __popcll(s1 ^ w1) +
             __popcll(s2 ^ w2) + __popcll(s3 ^ w3);
    float4 cc = ldsC[o];
    float xv = xp[(size_t)i * kHW];    // plain: L3-hit expected
    float u  = fmaf(cc.x, (float)(128 - kx), cc.y) + xv;
    float r  = u > 0.0f ? u : cc.z * u;
    __builtin_nontemporal_store(r + cc.w, op + (size_t)i * kHW);
  }
}

extern "C" void kernel_launch(void* const* d_in, const int* in_sizes, int n_in,
                              void* d_out, int out_size, void* d_ws, size_t ws_size,
                              hipStream_t stream) {
  const float* x     = (const float*)d_in[0];
  const float* bias0 = (const float*)d_in[1];
  const float* w     = (const float*)d_in[2];
  const float* gamma = (const float*)d_in[3];
  const float* beta  = (const float*)d_in[4];
  const float* bias1 = (const float*)d_in[5];
  const float* alpha = (const float*)d_in[6];
  const float* bias2 = (const float*)d_in[7];
  float* out = (float*)d_out;
  char*  ws  = (char*)d_ws;

  hipLaunchKernelGGL(prep_kernel, dim3(16), dim3(256), 0, stream, w, ws);
  hipLaunchKernelGGL(pack_stats_kernel, dim3(kBlkPk), dim3(256), 0, stream,
                     x, bias0, ws);
  hipLaunchKernelGGL(finalize_kernel, dim3(kBlkFn), dim3(256), 0, stream,
                     x, gamma, beta, bias1, alpha, bias2, ws, out);
}